// Round 1
// baseline (2319.547 us; speedup 1.0000x reference)
//
#include <hip/hip_runtime.h>
#include <math.h>

#define N_NODES 50000
#define D 128       // d_in == d_hid
#define D_OUT 64
#define NT 16       // nodes per block in layer kernels

// ---------------------------------------------------------------------------
// Scatter: agg[dst] += x[src]  (and optionally cnt[dst] += 1)
// 32 threads per edge, each handles 4 consecutive floats (float4 load).
// ---------------------------------------------------------------------------
__global__ __launch_bounds__(256) void scatter_kernel(
    const float* __restrict__ x,
    const int* __restrict__ src,
    const int* __restrict__ dst,
    float* __restrict__ agg,
    float* __restrict__ cnt,   // nullptr to skip counting
    int E)
{
    int tid = blockIdx.x * blockDim.x + threadIdx.x;
    int e = tid >> 5;          // edge index
    int lane = tid & 31;       // float4 slot within the 128-float row
    if (e >= E) return;
    int s = src[e];
    int d = dst[e];
    const float4 v = *reinterpret_cast<const float4*>(x + (size_t)s * D + lane * 4);
    float* o = agg + (size_t)d * D + lane * 4;
    atomicAdd(o + 0, v.x);
    atomicAdd(o + 1, v.y);
    atomicAdd(o + 2, v.z);
    atomicAdd(o + 3, v.w);
    if (cnt != nullptr && lane == 0) atomicAdd(cnt + d, 1.0f);
}

// ---------------------------------------------------------------------------
// Layer 1: h1[i][j] = relu( (agg[i]·Wl[j]) * inv_cnt[i] + b[j] + x[i]·Wr[j] )
// 128 threads (one per output feature j), NT nodes per block.
// Rows staged in LDS (broadcast reads); W streamed per-thread (L1-resident).
// ---------------------------------------------------------------------------
__global__ __launch_bounds__(128) void layer1_kernel(
    const float* __restrict__ agg,
    const float* __restrict__ x,
    const float* __restrict__ cnt,
    const float* __restrict__ Wl,
    const float* __restrict__ b,
    const float* __restrict__ Wr,
    float* __restrict__ h1,
    int n_nodes)
{
    __shared__ float sAgg[NT][D];
    __shared__ float sX[NT][D];
    __shared__ float sInv[NT];

    const int node0 = blockIdx.x * NT;
    const int j = threadIdx.x;

    // stage NT rows of agg and x (float4, coalesced)
    for (int idx = threadIdx.x; idx < NT * (D / 4); idx += 128) {
        int n  = idx / (D / 4);
        int k4 = idx % (D / 4);
        int node = node0 + n;
        float4 va = make_float4(0.f, 0.f, 0.f, 0.f);
        float4 vx = va;
        if (node < n_nodes) {
            va = *reinterpret_cast<const float4*>(agg + (size_t)node * D + k4 * 4);
            vx = *reinterpret_cast<const float4*>(x   + (size_t)node * D + k4 * 4);
        }
        *reinterpret_cast<float4*>(&sAgg[n][k4 * 4]) = va;
        *reinterpret_cast<float4*>(&sX[n][k4 * 4])   = vx;
    }
    if (threadIdx.x < NT) {
        int node = node0 + threadIdx.x;
        float c = (node < n_nodes) ? cnt[node] : 1.0f;
        sInv[threadIdx.x] = 1.0f / fmaxf(c, 1.0f);
    }
    __syncthreads();

    float accL[NT], accR[NT];
#pragma unroll
    for (int n = 0; n < NT; ++n) { accL[n] = 0.f; accR[n] = 0.f; }

    for (int k = 0; k < D; ++k) {
        float wl = Wl[(size_t)j * D + k];
        float wr = Wr[(size_t)j * D + k];
#pragma unroll
        for (int n = 0; n < NT; ++n) {
            accL[n] = fmaf(sAgg[n][k], wl, accL[n]);
            accR[n] = fmaf(sX[n][k],   wr, accR[n]);
        }
    }

    const float bj = b[j];
#pragma unroll
    for (int n = 0; n < NT; ++n) {
        int node = node0 + n;
        if (node < n_nodes) {
            float v = accL[n] * sInv[n] + bj + accR[n];
            h1[(size_t)node * D + j] = fmaxf(v, 0.0f);
        }
    }
}

// ---------------------------------------------------------------------------
// Layer 2 + log_softmax: z[j] = (agg[i]·Wl[j])*inv + b[j] + h1[i]·Wr[j]
// out[i][j] = z[j] - max - log(sum exp). 64 threads = 1 wave = one softmax row.
// ---------------------------------------------------------------------------
__global__ __launch_bounds__(64) void layer2_kernel(
    const float* __restrict__ agg,
    const float* __restrict__ h1,
    const float* __restrict__ cnt,
    const float* __restrict__ Wl,
    const float* __restrict__ b,
    const float* __restrict__ Wr,
    float* __restrict__ out,
    int n_nodes)
{
    __shared__ float sAgg[NT][D];
    __shared__ float sH[NT][D];
    __shared__ float sInv[NT];

    const int node0 = blockIdx.x * NT;
    const int j = threadIdx.x;   // 0..63

    for (int idx = threadIdx.x; idx < NT * (D / 4); idx += 64) {
        int n  = idx / (D / 4);
        int k4 = idx % (D / 4);
        int node = node0 + n;
        float4 va = make_float4(0.f, 0.f, 0.f, 0.f);
        float4 vh = va;
        if (node < n_nodes) {
            va = *reinterpret_cast<const float4*>(agg + (size_t)node * D + k4 * 4);
            vh = *reinterpret_cast<const float4*>(h1  + (size_t)node * D + k4 * 4);
        }
        *reinterpret_cast<float4*>(&sAgg[n][k4 * 4]) = va;
        *reinterpret_cast<float4*>(&sH[n][k4 * 4])   = vh;
    }
    if (threadIdx.x < NT) {
        int node = node0 + threadIdx.x;
        float c = (node < n_nodes) ? cnt[node] : 1.0f;
        sInv[threadIdx.x] = 1.0f / fmaxf(c, 1.0f);
    }
    __syncthreads();

    float accL[NT], accR[NT];
#pragma unroll
    for (int n = 0; n < NT; ++n) { accL[n] = 0.f; accR[n] = 0.f; }

    for (int k = 0; k < D; ++k) {
        float wl = Wl[(size_t)j * D + k];
        float wr = Wr[(size_t)j * D + k];
#pragma unroll
        for (int n = 0; n < NT; ++n) {
            accL[n] = fmaf(sAgg[n][k], wl, accL[n]);
            accR[n] = fmaf(sH[n][k],   wr, accR[n]);
        }
    }

    const float bj = b[j];
#pragma unroll
    for (int n = 0; n < NT; ++n) {
        float z = accL[n] * sInv[n] + bj + accR[n];
        // wave-wide (64-lane) max and sum-exp
        float m = z;
#pragma unroll
        for (int off = 32; off > 0; off >>= 1)
            m = fmaxf(m, __shfl_xor(m, off));
        float ex = expf(z - m);
        float sum = ex;
#pragma unroll
        for (int off = 32; off > 0; off >>= 1)
            sum += __shfl_xor(sum, off);
        float r = z - m - logf(sum);
        int node = node0 + n;
        if (node < n_nodes) out[(size_t)node * D_OUT + j] = r;
    }
}

// ---------------------------------------------------------------------------
extern "C" void kernel_launch(void* const* d_in, const int* in_sizes, int n_in,
                              void* d_out, int out_size, void* d_ws, size_t ws_size,
                              hipStream_t stream)
{
    const float* x   = (const float*)d_in[0];
    const int*   ei  = (const int*)d_in[1];     // int32 (JAX x64 disabled)
    const float* W1l = (const float*)d_in[2];
    const float* b1  = (const float*)d_in[3];
    const float* W1r = (const float*)d_in[4];
    const float* W2l = (const float*)d_in[5];
    const float* b2  = (const float*)d_in[6];
    const float* W2r = (const float*)d_in[7];
    float* out = (float*)d_out;

    const int E = in_sizes[1] / 2;
    const int* src = ei;
    const int* dst = ei + E;

    float* agg = (float*)d_ws;                       // N*D floats (reused both layers)
    float* h1  = agg + (size_t)N_NODES * D;          // N*D floats
    float* cnt = h1  + (size_t)N_NODES * D;          // N floats

    const size_t aggBytes = (size_t)N_NODES * D * sizeof(float);

    // ---- layer 1 ----
    hipMemsetAsync(agg, 0, aggBytes, stream);
    hipMemsetAsync(cnt, 0, (size_t)N_NODES * sizeof(float), stream);

    {
        long long total = (long long)E * 32;
        int blocks = (int)((total + 255) / 256);
        scatter_kernel<<<blocks, 256, 0, stream>>>(x, src, dst, agg, cnt, E);
    }
    {
        int blocks = (N_NODES + NT - 1) / NT;
        layer1_kernel<<<blocks, 128, 0, stream>>>(agg, x, cnt, W1l, b1, W1r, h1, N_NODES);
    }

    // ---- layer 2 ----
    hipMemsetAsync(agg, 0, aggBytes, stream);
    {
        long long total = (long long)E * 32;
        int blocks = (int)((total + 255) / 256);
        scatter_kernel<<<blocks, 256, 0, stream>>>(h1, src, dst, agg, nullptr, E);
    }
    {
        int blocks = (N_NODES + NT - 1) / NT;
        layer2_kernel<<<blocks, 64, 0, stream>>>(agg, h1, cnt, W2l, b2, W2r, out, N_NODES);
    }
}

// Round 2
// 486.954 us; speedup vs baseline: 4.7634x; 4.7634x over previous
//
#include <hip/hip_runtime.h>
#include <math.h>

#define N_NODES 50000
#define D 128       // d_in == d_hid
#define D_OUT 64
#define NT 16       // nodes per block in layer kernels

// ---------------------------------------------------------------------------
// CSR build step 1: in-degree histogram
// ---------------------------------------------------------------------------
__global__ __launch_bounds__(256) void hist_kernel(
    const int* __restrict__ dst, int* __restrict__ deg, int E)
{
    int e = blockIdx.x * blockDim.x + threadIdx.x;
    if (e < E) atomicAdd(&deg[dst[e]], 1);
}

// ---------------------------------------------------------------------------
// CSR build step 2: exclusive scan of deg -> row_ptr (single block)
// ---------------------------------------------------------------------------
__global__ __launch_bounds__(256) void scan_kernel(
    const int* __restrict__ deg, int* __restrict__ row_ptr, int n)
{
    __shared__ int sums[256];
    __shared__ int excl[256];
    const int t = threadIdx.x;
    const int chunk = (n + 255) / 256;
    const int start = t * chunk;
    const int end   = min(start + chunk, n);

    int s = 0;
    for (int i = start; i < end; ++i) s += deg[i];
    sums[t] = s;
    __syncthreads();

    if (t == 0) {
        int run = 0;
        for (int i = 0; i < 256; ++i) { excl[i] = run; run += sums[i]; }
        row_ptr[n] = run;
    }
    __syncthreads();

    int run = excl[t];
    for (int i = start; i < end; ++i) { row_ptr[i] = run; run += deg[i]; }
}

// ---------------------------------------------------------------------------
// CSR build step 3: bucket-fill edge sources (order within bucket arbitrary)
// ---------------------------------------------------------------------------
__global__ __launch_bounds__(256) void fill_kernel(
    const int* __restrict__ src, const int* __restrict__ dst,
    const int* __restrict__ row_ptr, int* __restrict__ cursor,
    int* __restrict__ esrc, int E)
{
    int e = blockIdx.x * blockDim.x + threadIdx.x;
    if (e >= E) return;
    int d = dst[e];
    int pos = atomicAdd(&cursor[d], 1);
    esrc[row_ptr[d] + pos] = src[e];
}

// ---------------------------------------------------------------------------
// Gather-aggregate: one 64-lane wave per node, float2 per lane (128 floats).
// Writes the premeaned row: agg[i] = sum_{j->i} x[j] / max(deg,1).
// ---------------------------------------------------------------------------
__global__ __launch_bounds__(256) void gather_agg_kernel(
    const float* __restrict__ x,
    const int* __restrict__ row_ptr,
    const int* __restrict__ esrc,
    float* __restrict__ agg,
    int n_nodes)
{
    int gtid = blockIdx.x * blockDim.x + threadIdx.x;
    int node = gtid >> 6;
    int lane = gtid & 63;
    if (node >= n_nodes) return;

    int beg = row_ptr[node];
    int end = row_ptr[node + 1];

    float ax = 0.f, ay = 0.f;
    int p = beg;
    for (; p + 1 < end; p += 2) {
        int s0 = esrc[p];
        int s1 = esrc[p + 1];
        const float2 v0 = *reinterpret_cast<const float2*>(x + (size_t)s0 * D + lane * 2);
        const float2 v1 = *reinterpret_cast<const float2*>(x + (size_t)s1 * D + lane * 2);
        ax += v0.x + v1.x;
        ay += v0.y + v1.y;
    }
    if (p < end) {
        int s0 = esrc[p];
        const float2 v0 = *reinterpret_cast<const float2*>(x + (size_t)s0 * D + lane * 2);
        ax += v0.x;
        ay += v0.y;
    }

    float inv = (end > beg) ? 1.0f / (float)(end - beg) : 0.0f;
    *reinterpret_cast<float2*>(agg + (size_t)node * D + lane * 2) =
        make_float2(ax * inv, ay * inv);
}

// ---------------------------------------------------------------------------
// Layer 1: h1[i][j] = relu( aggm[i]·Wl[j] + b[j] + x[i]·Wr[j] )   (agg premeaned)
// ---------------------------------------------------------------------------
__global__ __launch_bounds__(128) void layer1_kernel(
    const float* __restrict__ aggm,
    const float* __restrict__ x,
    const float* __restrict__ Wl,
    const float* __restrict__ b,
    const float* __restrict__ Wr,
    float* __restrict__ h1,
    int n_nodes)
{
    __shared__ float sAgg[NT][D];
    __shared__ float sX[NT][D];

    const int node0 = blockIdx.x * NT;
    const int j = threadIdx.x;

    for (int idx = threadIdx.x; idx < NT * (D / 4); idx += 128) {
        int n  = idx / (D / 4);
        int k4 = idx % (D / 4);
        int node = node0 + n;
        float4 va = make_float4(0.f, 0.f, 0.f, 0.f);
        float4 vx = va;
        if (node < n_nodes) {
            va = *reinterpret_cast<const float4*>(aggm + (size_t)node * D + k4 * 4);
            vx = *reinterpret_cast<const float4*>(x    + (size_t)node * D + k4 * 4);
        }
        *reinterpret_cast<float4*>(&sAgg[n][k4 * 4]) = va;
        *reinterpret_cast<float4*>(&sX[n][k4 * 4])   = vx;
    }
    __syncthreads();

    float accL[NT], accR[NT];
#pragma unroll
    for (int n = 0; n < NT; ++n) { accL[n] = 0.f; accR[n] = 0.f; }

    for (int k = 0; k < D; ++k) {
        float wl = Wl[(size_t)j * D + k];
        float wr = Wr[(size_t)j * D + k];
#pragma unroll
        for (int n = 0; n < NT; ++n) {
            accL[n] = fmaf(sAgg[n][k], wl, accL[n]);
            accR[n] = fmaf(sX[n][k],   wr, accR[n]);
        }
    }

    const float bj = b[j];
#pragma unroll
    for (int n = 0; n < NT; ++n) {
        int node = node0 + n;
        if (node < n_nodes) {
            float v = accL[n] + bj + accR[n];
            h1[(size_t)node * D + j] = fmaxf(v, 0.0f);
        }
    }
}

// ---------------------------------------------------------------------------
// Layer 2 + log_softmax (agg premeaned)
// ---------------------------------------------------------------------------
__global__ __launch_bounds__(64) void layer2_kernel(
    const float* __restrict__ aggm,
    const float* __restrict__ h1,
    const float* __restrict__ Wl,
    const float* __restrict__ b,
    const float* __restrict__ Wr,
    float* __restrict__ out,
    int n_nodes)
{
    __shared__ float sAgg[NT][D];
    __shared__ float sH[NT][D];

    const int node0 = blockIdx.x * NT;
    const int j = threadIdx.x;   // 0..63

    for (int idx = threadIdx.x; idx < NT * (D / 4); idx += 64) {
        int n  = idx / (D / 4);
        int k4 = idx % (D / 4);
        int node = node0 + n;
        float4 va = make_float4(0.f, 0.f, 0.f, 0.f);
        float4 vh = va;
        if (node < n_nodes) {
            va = *reinterpret_cast<const float4*>(aggm + (size_t)node * D + k4 * 4);
            vh = *reinterpret_cast<const float4*>(h1   + (size_t)node * D + k4 * 4);
        }
        *reinterpret_cast<float4*>(&sAgg[n][k4 * 4]) = va;
        *reinterpret_cast<float4*>(&sH[n][k4 * 4])   = vh;
    }
    __syncthreads();

    float accL[NT], accR[NT];
#pragma unroll
    for (int n = 0; n < NT; ++n) { accL[n] = 0.f; accR[n] = 0.f; }

    for (int k = 0; k < D; ++k) {
        float wl = Wl[(size_t)j * D + k];
        float wr = Wr[(size_t)j * D + k];
#pragma unroll
        for (int n = 0; n < NT; ++n) {
            accL[n] = fmaf(sAgg[n][k], wl, accL[n]);
            accR[n] = fmaf(sH[n][k],   wr, accR[n]);
        }
    }

    const float bj = b[j];
#pragma unroll
    for (int n = 0; n < NT; ++n) {
        float z = accL[n] + bj + accR[n];
        float m = z;
#pragma unroll
        for (int off = 32; off > 0; off >>= 1)
            m = fmaxf(m, __shfl_xor(m, off));
        float ex = expf(z - m);
        float sum = ex;
#pragma unroll
        for (int off = 32; off > 0; off >>= 1)
            sum += __shfl_xor(sum, off);
        float r = z - m - logf(sum);
        int node = node0 + n;
        if (node < n_nodes) out[(size_t)node * D_OUT + j] = r;
    }
}

// ---------------------------------------------------------------------------
extern "C" void kernel_launch(void* const* d_in, const int* in_sizes, int n_in,
                              void* d_out, int out_size, void* d_ws, size_t ws_size,
                              hipStream_t stream)
{
    const float* x   = (const float*)d_in[0];
    const int*   ei  = (const int*)d_in[1];
    const float* W1l = (const float*)d_in[2];
    const float* b1  = (const float*)d_in[3];
    const float* W1r = (const float*)d_in[4];
    const float* W2l = (const float*)d_in[5];
    const float* b2  = (const float*)d_in[6];
    const float* W2r = (const float*)d_in[7];
    float* out = (float*)d_out;

    const int E = in_sizes[1] / 2;
    const int* src = ei;
    const int* dst = ei + E;

    // workspace layout (floats/ints, all 4B)
    float* agg     = (float*)d_ws;                       // N*D
    float* h1      = agg + (size_t)N_NODES * D;          // N*D
    int*   deg     = (int*)(h1 + (size_t)N_NODES * D);   // N
    int*   row_ptr = deg + N_NODES;                      // N+1
    int*   cursor  = row_ptr + N_NODES + 1;              // N
    int*   esrc    = cursor + N_NODES;                   // E

    const int EB = (E + 255) / 256;

    // ---- CSR build (once; shared by both layers) ----
    hipMemsetAsync(deg,    0, (size_t)N_NODES * sizeof(int), stream);
    hipMemsetAsync(cursor, 0, (size_t)N_NODES * sizeof(int), stream);
    hist_kernel<<<EB, 256, 0, stream>>>(dst, deg, E);
    scan_kernel<<<1, 256, 0, stream>>>(deg, row_ptr, N_NODES);
    fill_kernel<<<EB, 256, 0, stream>>>(src, dst, row_ptr, cursor, esrc, E);

    const int GB = (N_NODES * 64 + 255) / 256;   // gather: 1 wave per node
    const int LB = (N_NODES + NT - 1) / NT;

    // ---- layer 1 ----
    gather_agg_kernel<<<GB, 256, 0, stream>>>(x, row_ptr, esrc, agg, N_NODES);
    layer1_kernel<<<LB, 128, 0, stream>>>(agg, x, W1l, b1, W1r, h1, N_NODES);

    // ---- layer 2 ----
    gather_agg_kernel<<<GB, 256, 0, stream>>>(h1, row_ptr, esrc, agg, N_NODES);
    layer2_kernel<<<LB, 64, 0, stream>>>(agg, h1, W2l, b2, W2r, out, N_NODES);
}